// Round 2
// baseline (20.205 us; speedup 1.0000x reference)
//
#include <hip/hip_runtime.h>

// StructuredPerceptron: B=32, S=2048, T=512
// loss = sum_b max(pred_score_b - gold_score_b, 0)
// score_b = sum_{s<L} unary[b,s,tag[s]] + sum_{1<=s<L} binary[tag[s-1],tag[s]]
// L = sum_s mask[b,s]
//
// Single fused kernel: 32 blocks (one per batch), each atomicAdd's its
// ReLU'd loss into d_out[0], which a 4-byte memset node zeroes first.
// Gathers are issued unconditionally BEFORE the seq_len reduce so the
// L3-latency of the scattered unary/binary loads overlaps the mask
// reduction + barrier; the s<L predicate is applied at accumulate time.

#define BB 32
#define SS 2048
#define TT 512

__global__ __launch_bounds__(256) void sp_fused_kernel(
    const float* __restrict__ unary,
    const float* __restrict__ binary,
    const int*   __restrict__ tags,
    const int*   __restrict__ pred,
    const int*   __restrict__ mask,
    float*       __restrict__ out)
{
    const int b    = blockIdx.x;
    const int tid  = threadIdx.x;
    const int wave = tid >> 6;

    __shared__ int   s_ipart[4];
    __shared__ float s_part[8];
    __shared__ int   s_len;

    // ---- issue everything up front: mask loads + all gathers ----
    int m = 0;
    float vg[8], vp[8];
    #pragma unroll
    for (int k = 0; k < 8; ++k) {
        const int s    = tid + k * 256;
        const int base = b * SS + s;
        const int tg = tags[base];
        const int tp = pred[base];
        m += mask[base];
        float g = unary[base * TT + tg];
        float p = unary[base * TT + tp];
        if (s >= 1) {
            const int tg0 = tags[base - 1];
            const int tp0 = pred[base - 1];
            g += binary[tg0 * TT + tg];
            p += binary[tp0 * TT + tp];
        }
        vg[k] = g;
        vp[k] = p;
    }

    // ---- seq_len reduce (overlaps in-flight gathers) ----
    #pragma unroll
    for (int off = 32; off > 0; off >>= 1) m += __shfl_down(m, off);
    if ((tid & 63) == 0) s_ipart[wave] = m;
    __syncthreads();
    if (tid == 0) s_len = s_ipart[0] + s_ipart[1] + s_ipart[2] + s_ipart[3];
    __syncthreads();
    const int L = s_len;

    // ---- predicated accumulate ----
    float g = 0.f, p = 0.f;
    #pragma unroll
    for (int k = 0; k < 8; ++k) {
        const int s = tid + k * 256;
        if (s < L) { g += vg[k]; p += vp[k]; }
    }
    #pragma unroll
    for (int off = 32; off > 0; off >>= 1) {
        g += __shfl_down(g, off);
        p += __shfl_down(p, off);
    }
    if ((tid & 63) == 0) { s_part[wave * 2] = g; s_part[wave * 2 + 1] = p; }
    __syncthreads();
    if (tid == 0) {
        const float G = s_part[0] + s_part[2] + s_part[4] + s_part[6];
        const float P = s_part[1] + s_part[3] + s_part[5] + s_part[7];
        atomicAdd(out, fmaxf(P - G, 0.f));
    }
}

extern "C" void kernel_launch(void* const* d_in, const int* in_sizes, int n_in,
                              void* d_out, int out_size, void* d_ws, size_t ws_size,
                              hipStream_t stream) {
    const float* unary  = (const float*)d_in[0];
    const float* binary = (const float*)d_in[1];
    const int*   tags   = (const int*)d_in[2];
    const int*   pred   = (const int*)d_in[3];
    const int*   mask   = (const int*)d_in[4];
    float* out = (float*)d_out;

    hipMemsetAsync(out, 0, sizeof(float), stream);
    sp_fused_kernel<<<BB, 256, 0, stream>>>(unary, binary, tags, pred, mask, out);
}

// Round 3
// 12.527 us; speedup vs baseline: 1.6129x; 1.6129x over previous
//
#include <hip/hip_runtime.h>

// StructuredPerceptron: B=32, S=2048, T=512
// loss = sum_b max(pred_score_b - gold_score_b, 0)
// score_b = sum_{s<L} unary[b,s,tag[s]] + sum_{1<=s<L} binary[tag[s-1],tag[s]]
// L = sum_s mask[b,s]
//
// SINGLE graph node (R2 lesson: a memset node costs as much as a kernel
// dispatch ~4-5us). Blocks publish per-batch (G,P) to d_ws; the last block
// to arrive (module-scope __device__ counter -- never poisoned by the
// harness, restored to 0 before exit so the invariant holds across graph
// replays and the initial correctness call) sums the 32 ReLU'd losses in a
// fixed serial order (bitwise deterministic) and writes d_out[0].

#define BB 32
#define SS 2048
#define TT 512

__device__ int sp_counter = 0;  // invariant: ==0 whenever no kernel in flight

__global__ __launch_bounds__(256) void sp_fused_kernel(
    const float* __restrict__ unary,
    const float* __restrict__ binary,
    const int*   __restrict__ tags,
    const int*   __restrict__ pred,
    const int*   __restrict__ mask,
    float*       __restrict__ ws,
    float*       __restrict__ out)
{
    const int b    = blockIdx.x;
    const int tid  = threadIdx.x;
    const int wave = tid >> 6;

    __shared__ int   s_ipart[4];
    __shared__ float s_part[8];
    __shared__ int   s_len;

    // ---- seq_len = sum(mask[b,:])  (coalesced, 8KB) ----
    int m = 0;
    for (int s = tid; s < SS; s += 256) m += mask[b * SS + s];
    #pragma unroll
    for (int off = 32; off > 0; off >>= 1) m += __shfl_down(m, off);
    if ((tid & 63) == 0) s_ipart[wave] = m;
    __syncthreads();
    if (tid == 0) s_len = s_ipart[0] + s_ipart[1] + s_ipart[2] + s_ipart[3];
    __syncthreads();
    const int L = s_len;

    // ---- predicated gathers (only s < L issues scattered loads) ----
    float g = 0.f, p = 0.f;
    for (int s = tid; s < SS; s += 256) {
        if (s < L) {
            const int base = b * SS + s;
            const int tg = tags[base];
            const int tp = pred[base];
            g += unary[base * TT + tg];
            p += unary[base * TT + tp];
            if (s >= 1) {
                const int tg0 = tags[base - 1];
                const int tp0 = pred[base - 1];
                g += binary[tg0 * TT + tg];
                p += binary[tp0 * TT + tp];
            }
        }
    }
    #pragma unroll
    for (int off = 32; off > 0; off >>= 1) {
        g += __shfl_down(g, off);
        p += __shfl_down(p, off);
    }
    if ((tid & 63) == 0) { s_part[wave * 2] = g; s_part[wave * 2 + 1] = p; }
    __syncthreads();

    if (tid == 0) {
        const float G = s_part[0] + s_part[2] + s_part[4] + s_part[6];
        const float P = s_part[1] + s_part[3] + s_part[5] + s_part[7];
        ws[2 * b]     = G;
        ws[2 * b + 1] = P;
        __threadfence();                        // publish ws before arrival
        const int old = atomicAdd(&sp_counter, 1);
        if (old == BB - 1) {                    // last block: finish
            __threadfence();                    // acquire all ws writes
            float total = 0.f;
            for (int i = 0; i < BB; ++i) {      // fixed order -> deterministic
                const float Gi = ws[2 * i];
                const float Pi = ws[2 * i + 1];
                total += fmaxf(Pi - Gi, 0.f);
            }
            out[0] = total;
            atomicExch(&sp_counter, 0);         // restore invariant for replay
        }
    }
}

extern "C" void kernel_launch(void* const* d_in, const int* in_sizes, int n_in,
                              void* d_out, int out_size, void* d_ws, size_t ws_size,
                              hipStream_t stream) {
    const float* unary  = (const float*)d_in[0];
    const float* binary = (const float*)d_in[1];
    const int*   tags   = (const int*)d_in[2];
    const int*   pred   = (const int*)d_in[3];
    const int*   mask   = (const int*)d_in[4];
    float* ws  = (float*)d_ws;
    float* out = (float*)d_out;

    sp_fused_kernel<<<BB, 256, 0, stream>>>(unary, binary, tags, pred, mask, ws, out);
}

// Round 4
// 11.055 us; speedup vs baseline: 1.8278x; 1.1332x over previous
//
#include <hip/hip_runtime.h>

// StructuredPerceptron: B=32, S=2048, T=512
// loss = sum_b max(pred_score_b - gold_score_b, 0)
// score_b = sum_{s<L} unary[b,s,tag[s]] + sum_{1<=s<L} binary[tag[s-1],tag[s]]
// L = sum_s mask[b,s]
//
// Single graph node (R2/R3 lesson: memset nodes cost ~7us; kernel-node
// count 2->1 changed nothing -> we sit near the graph-replay floor).
// This version removes one serial L3-latency stage: all coalesced streams
// (mask, tags, preds, shifted tags/preds) are prefetched into registers
// BEFORE the seq_len reduce; only the scattered unary/binary gathers wait
// for L (and stay predicated, so no R2-style double-gather cost).

#define BB 32
#define SS 2048
#define TT 512

__device__ int sp_counter = 0;  // invariant: ==0 whenever no kernel in flight

__global__ __launch_bounds__(256) void sp_fused_kernel(
    const float* __restrict__ unary,
    const float* __restrict__ binary,
    const int*   __restrict__ tags,
    const int*   __restrict__ pred,
    const int*   __restrict__ mask,
    float*       __restrict__ ws,
    float*       __restrict__ out)
{
    const int b    = blockIdx.x;
    const int tid  = threadIdx.x;
    const int wave = tid >> 6;

    __shared__ int   s_ipart[4];
    __shared__ float s_part[8];
    __shared__ int   s_len;

    // ---- prefetch ALL coalesced streams up front (independent of L) ----
    int mk[8], tg[8], tp[8], tg0[8], tp0[8];
    #pragma unroll
    for (int k = 0; k < 8; ++k) {
        const int s    = tid + k * 256;
        const int base = b * SS + s;
        mk[k]  = mask[base];
        tg[k]  = tags[base];
        tp[k]  = pred[base];
        tg0[k] = (s >= 1) ? tags[base - 1] : 0;
        tp0[k] = (s >= 1) ? pred[base - 1] : 0;
    }

    // ---- seq_len reduce (overlaps the in-flight tag/pred loads) ----
    int m = 0;
    #pragma unroll
    for (int k = 0; k < 8; ++k) m += mk[k];
    #pragma unroll
    for (int off = 32; off > 0; off >>= 1) m += __shfl_down(m, off);
    if ((tid & 63) == 0) s_ipart[wave] = m;
    __syncthreads();
    if (tid == 0) s_len = s_ipart[0] + s_ipart[1] + s_ipart[2] + s_ipart[3];
    __syncthreads();
    const int L = s_len;

    // ---- predicated scattered gathers (tags already in registers) ----
    float g = 0.f, p = 0.f;
    #pragma unroll
    for (int k = 0; k < 8; ++k) {
        const int s    = tid + k * 256;
        const int base = b * SS + s;
        if (s < L) {
            g += unary[base * TT + tg[k]];
            p += unary[base * TT + tp[k]];
            if (s >= 1) {
                g += binary[tg0[k] * TT + tg[k]];
                p += binary[tp0[k] * TT + tp[k]];
            }
        }
    }
    #pragma unroll
    for (int off = 32; off > 0; off >>= 1) {
        g += __shfl_down(g, off);
        p += __shfl_down(p, off);
    }
    if ((tid & 63) == 0) { s_part[wave * 2] = g; s_part[wave * 2 + 1] = p; }
    __syncthreads();

    if (tid == 0) {
        const float G = s_part[0] + s_part[2] + s_part[4] + s_part[6];
        const float P = s_part[1] + s_part[3] + s_part[5] + s_part[7];
        ws[2 * b]     = G;
        ws[2 * b + 1] = P;
        __threadfence();                        // publish ws before arrival
        const int old = atomicAdd(&sp_counter, 1);
        if (old == BB - 1) {                    // last block: finish
            __threadfence();                    // acquire all ws writes
            float total = 0.f;
            for (int i = 0; i < BB; ++i) {      // fixed order -> deterministic
                const float Gi = ws[2 * i];
                const float Pi = ws[2 * i + 1];
                total += fmaxf(Pi - Gi, 0.f);
            }
            out[0] = total;
            atomicExch(&sp_counter, 0);         // restore invariant for replay
        }
    }
}

extern "C" void kernel_launch(void* const* d_in, const int* in_sizes, int n_in,
                              void* d_out, int out_size, void* d_ws, size_t ws_size,
                              hipStream_t stream) {
    const float* unary  = (const float*)d_in[0];
    const float* binary = (const float*)d_in[1];
    const int*   tags   = (const int*)d_in[2];
    const int*   pred   = (const int*)d_in[3];
    const int*   mask   = (const int*)d_in[4];
    float* ws  = (float*)d_ws;
    float* out = (float*)d_out;

    sp_fused_kernel<<<BB, 256, 0, stream>>>(unary, binary, tags, pred, mask, ws, out);
}